// Round 1
// baseline (141.662 us; speedup 1.0000x reference)
//
#include <hip/hip_runtime.h>
#include <hip/hip_bf16.h>

// ToneMappingCurveLoss: luma-binned mean-difference loss.
// Inputs: pred, target, input_img: [16, 3, 512, 512] f32. Output: 1 f32 scalar.
// HW = 512*512 = 262144 = 2^18 ; float4 groups per channel = 65536 = 2^16.

#define CH4 65536         // HW/4
#define NBINS 16

__device__ __forceinline__ float luma_exact(float r, float g, float b) {
    // match numpy/jax f32 evaluation order, no FMA contraction
    return __fadd_rn(__fadd_rn(__fmul_rn(0.299f, r), __fmul_rn(0.587f, g)),
                     __fmul_rn(0.114f, b));
}

__global__ __launch_bounds__(256) void tm_stage1(
    const float4* __restrict__ pred,
    const float4* __restrict__ target,
    const float4* __restrict__ input,
    float* __restrict__ partials,   // [gridDim.x][48]
    int G)                          // total float4 pixel-groups (B*HW/4)
{
    __shared__ float h[3 * NBINS];
    const int t = threadIdx.x;
    if (t < 3 * NBINS) h[t] = 0.0f;
    __syncthreads();

    const int T = gridDim.x * 256;
    for (int g = blockIdx.x * 256 + t; g < G; g += T) {
        const int b = g >> 16;          // image index
        const int q = g & (CH4 - 1);    // float4 group within image
        const int base = b * (3 * CH4) + q;

        const float4 p0 = pred[base];
        const float4 p1 = pred[base + CH4];
        const float4 p2 = pred[base + 2 * CH4];
        const float4 t0 = target[base];
        const float4 t1 = target[base + CH4];
        const float4 t2 = target[base + 2 * CH4];
        const float4 i0 = input[base];
        const float4 i1 = input[base + CH4];
        const float4 i2 = input[base + 2 * CH4];

        const float ir[4] = {i0.x, i0.y, i0.z, i0.w};
        const float ig[4] = {i1.x, i1.y, i1.z, i1.w};
        const float ib[4] = {i2.x, i2.y, i2.z, i2.w};
        const float pr[4] = {p0.x, p0.y, p0.z, p0.w};
        const float pg[4] = {p1.x, p1.y, p1.z, p1.w};
        const float pb[4] = {p2.x, p2.y, p2.z, p2.w};
        const float tr[4] = {t0.x, t0.y, t0.z, t0.w};
        const float tg[4] = {t1.x, t1.y, t1.z, t1.w};
        const float tb[4] = {t2.x, t2.y, t2.z, t2.w};

        #pragma unroll
        for (int j = 0; j < 4; ++j) {
            const float il = luma_exact(ir[j], ig[j], ib[j]);
            if (il < 1.0f) {
                int bin = (int)floorf(__fmul_rn(il, 16.0f));
                bin = min(max(bin, 0), NBINS - 1);
                const float pl = luma_exact(pr[j], pg[j], pb[j]);
                const float tl = luma_exact(tr[j], tg[j], tb[j]);
                atomicAdd(&h[bin], 1.0f);
                atomicAdd(&h[NBINS + bin], pl);
                atomicAdd(&h[2 * NBINS + bin], tl);
            }
        }
    }

    __syncthreads();
    if (t < 3 * NBINS) partials[blockIdx.x * (3 * NBINS) + t] = h[t];
}

__global__ __launch_bounds__(512) void tm_stage2(
    const float* __restrict__ partials, int rows, float* __restrict__ out)
{
    __shared__ double col[3 * NBINS];
    const int t = threadIdx.x;
    if (t < 8 * 3 * NBINS) {            // 384 active threads, 8 per column
        const int c = t >> 3;
        const int l = t & 7;
        double s = 0.0;
        for (int r = l; r < rows; r += 8)
            s += (double)partials[r * (3 * NBINS) + c];
        // reduce the 8-lane group (consecutive lanes, same wave)
        #pragma unroll
        for (int k = 4; k; k >>= 1) s += __shfl_down(s, k, 8);
        if (l == 0) col[c] = s;
    }
    __syncthreads();
    if (t == 0) {
        double acc = 0.0;
        #pragma unroll
        for (int i = 0; i < NBINS; ++i) {
            const double cnt = col[i];
            if (cnt > 0.0) {
                const double ps = col[NBINS + i] / cnt;
                const double ts = col[2 * NBINS + i] / cnt;
                acc += fabs(ps - ts);
            }
        }
        out[0] = (float)(acc / (double)NBINS);
    }
}

extern "C" void kernel_launch(void* const* d_in, const int* in_sizes, int n_in,
                              void* d_out, int out_size, void* d_ws, size_t ws_size,
                              hipStream_t stream) {
    const float* pred   = (const float*)d_in[0];
    const float* target = (const float*)d_in[1];
    const float* input  = (const float*)d_in[2];

    // in_sizes[0] = B*3*H*W ; pixel float4-groups = size / (3*4)
    const int G = in_sizes[0] / 12;

    int blocks = 2048;
    const size_t maxRows = ws_size / (3 * NBINS * sizeof(float));
    if ((size_t)blocks > maxRows) blocks = (int)maxRows;
    if (blocks < 1) blocks = 1;

    tm_stage1<<<blocks, 256, 0, stream>>>(
        (const float4*)pred, (const float4*)target, (const float4*)input,
        (float*)d_ws, G);
    tm_stage2<<<1, 512, 0, stream>>>((const float*)d_ws, blocks, (float*)d_out);
}

// Round 2
// 87.307 us; speedup vs baseline: 1.6226x; 1.6226x over previous
//
#include <hip/hip_runtime.h>
#include <hip/hip_bf16.h>

// ToneMappingCurveLoss: luma-binned mean-difference loss.
// Inputs: pred, target, input_img: [16, 3, 512, 512] f32. Output: 1 f32 scalar.
// HW = 512*512 = 262144 = 2^18 ; float4 groups per channel = 65536 = 2^16.

#define CH4 65536         // HW/4
#define NBINS 16
#define NCOL (3 * NBINS)  // 48 accumulated columns: count, psum, tsum per bin
#define COPIES 64         // per-lane privatized histogram copies

__device__ __forceinline__ float luma_exact(float r, float g, float b) {
    // match numpy/jax f32 evaluation order, no FMA contraction
    return __fadd_rn(__fadd_rn(__fmul_rn(0.299f, r), __fmul_rn(0.587f, g)),
                     __fmul_rn(0.114f, b));
}

__global__ __launch_bounds__(256) void tm_stage1(
    const float4* __restrict__ pred,
    const float4* __restrict__ target,
    const float4* __restrict__ input,
    float* __restrict__ partials,   // column-major [NCOL][rows]
    int G, int rows)
{
    // h[c][lane]: per-lane copies -> no within-wave same-address atomics.
    // addr bank = lane%32 -> 2 lanes/bank (free). 12 KB LDS.
    __shared__ float h[NCOL * COPIES];
    const int t = threadIdx.x;
    const int lane = t & 63;

    for (int i = t; i < NCOL * COPIES; i += 256) h[i] = 0.0f;
    __syncthreads();

    const int T = gridDim.x * 256;
    for (int g = blockIdx.x * 256 + t; g < G; g += T) {
        const int b = g >> 16;          // image index
        const int q = g & (CH4 - 1);    // float4 group within image
        const int base = b * (3 * CH4) + q;

        const float4 i0 = input[base];
        const float4 i1 = input[base + CH4];
        const float4 i2 = input[base + 2 * CH4];
        const float4 p0 = pred[base];
        const float4 p1 = pred[base + CH4];
        const float4 p2 = pred[base + 2 * CH4];
        const float4 t0 = target[base];
        const float4 t1 = target[base + CH4];
        const float4 t2 = target[base + 2 * CH4];

        const float ir[4] = {i0.x, i0.y, i0.z, i0.w};
        const float ig[4] = {i1.x, i1.y, i1.z, i1.w};
        const float ib[4] = {i2.x, i2.y, i2.z, i2.w};
        const float pr[4] = {p0.x, p0.y, p0.z, p0.w};
        const float pg[4] = {p1.x, p1.y, p1.z, p1.w};
        const float pb[4] = {p2.x, p2.y, p2.z, p2.w};
        const float tr[4] = {t0.x, t0.y, t0.z, t0.w};
        const float tg[4] = {t1.x, t1.y, t1.z, t1.w};
        const float tb[4] = {t2.x, t2.y, t2.z, t2.w};

        #pragma unroll
        for (int j = 0; j < 4; ++j) {
            const float il = luma_exact(ir[j], ig[j], ib[j]);
            if (il < 1.0f) {
                int bin = (int)floorf(__fmul_rn(il, 16.0f));
                bin = min(max(bin, 0), NBINS - 1);
                const float pl = luma_exact(pr[j], pg[j], pb[j]);
                const float tl = luma_exact(tr[j], tg[j], tb[j]);
                atomicAdd(&h[bin * COPIES + lane], 1.0f);
                atomicAdd(&h[(NBINS + bin) * COPIES + lane], pl);
                atomicAdd(&h[(2 * NBINS + bin) * COPIES + lane], tl);
            }
        }
    }

    __syncthreads();
    // Reduce 64 per-lane copies -> one value per column, via shuffle tree.
    if (t < 64) {
        #pragma unroll
        for (int c = 0; c < NCOL; ++c) {
            float v = h[c * COPIES + t];
            v += __shfl_down(v, 32);
            v += __shfl_down(v, 16);
            v += __shfl_down(v, 8);
            v += __shfl_down(v, 4);
            v += __shfl_down(v, 2);
            v += __shfl_down(v, 1);
            if (t == 0) partials[c * rows + blockIdx.x] = v;
        }
    }
}

__global__ __launch_bounds__(768) void tm_stage2(
    const float4* __restrict__ partials4,  // column-major [NCOL][rows/4] float4
    float* __restrict__ out, int rows4)
{
    __shared__ double col[NCOL];
    const int t = threadIdx.x;          // 768 = 48 cols x 16 threads
    const int c = t >> 4;
    const int l = t & 15;

    double s = 0.0;
    for (int k = l; k < rows4; k += 16) {   // 8 independent float4 loads (ILP)
        const float4 v = partials4[c * rows4 + k];
        s += (double)v.x + (double)v.y + (double)v.z + (double)v.w;
    }
    #pragma unroll
    for (int k = 8; k; k >>= 1) s += __shfl_down(s, k, 16);
    if (l == 0) col[c] = s;
    __syncthreads();

    if (t == 0) {
        double acc = 0.0;
        #pragma unroll
        for (int i = 0; i < NBINS; ++i) {
            const double cnt = col[i];
            if (cnt > 0.0) {
                acc += fabs(col[NBINS + i] / cnt - col[2 * NBINS + i] / cnt);
            }
        }
        out[0] = (float)(acc / (double)NBINS);
    }
}

extern "C" void kernel_launch(void* const* d_in, const int* in_sizes, int n_in,
                              void* d_out, int out_size, void* d_ws, size_t ws_size,
                              hipStream_t stream) {
    const float* pred   = (const float*)d_in[0];
    const float* target = (const float*)d_in[1];
    const float* input  = (const float*)d_in[2];

    // in_sizes[0] = B*3*H*W ; pixel float4-groups = size / (3*4)
    const int G = in_sizes[0] / 12;

    // rows (= stage1 grid) : 512 blocks -> 2 blocks/CU, multiple of 64 for
    // float4 stage2 loads; clamp to workspace capacity.
    int rows = 512;
    const size_t maxRows = ws_size / (NCOL * sizeof(float));
    while ((size_t)rows > maxRows && rows > 64) rows >>= 1;

    tm_stage1<<<rows, 256, 0, stream>>>(
        (const float4*)pred, (const float4*)target, (const float4*)input,
        (float*)d_ws, G, rows);
    tm_stage2<<<1, 768, 0, stream>>>((const float4*)d_ws, (float*)d_out, rows / 4);
}